// Round 1
// 215.356 us; speedup vs baseline: 1.0094x; 1.0094x over previous
//
#include <hip/hip_runtime.h>

// SpikingLayer: T=64 sequential steps over [B=32, F=16384] fp32 state.
//   state = (x + state) - act
//   state = max(state + 1.0f, 0.0f) - 1.0f   // bit-exact relu(s+1)-1, NOT max(s,-1)
//   act   = state > 0 ? floor(state) : 0
// 134 MB in + 134 MB out => 42.7 us floor at 6.29 TB/s measured copy ceiling.
//
// History:
// R2: float4, depth-2, 8 waves/CU  -> ~71 us (kernel dispatch)
// R3: scalar, depth-8, 32 waves/CU -> ~82 us  (more TLP, slower: vmem instr efficiency wins)
// R6: float4 + depth-8 ring + nontemporal        -> ~57 us kernel (217 total incl. 2x80us harness fills)
// R7 (this): phase-grouped streams. The R6 loop alternated 1 load / 1 store per
// step -> HBM sees 1 KB-granularity direction flips, and in-order vmcnt retirement
// makes every load-wait transitively wait on interleaved older stores.
// Fix: 8-step phases, double-buffered: burst 8 loads (8 KB/wave, one direction),
// compute 8 steps, burst 8 stores (8 KB/wave). Loads for group g+1 are issued
// BEFORE compute of group g -> a full compute+store phase of latency hiding,
// with only loads between a load's issue and its waitcnt.

#define T_STEPS 64
#define NCHAINS (32 * 16384)       // B*F = 524288 independent chains
#define NCHAINS4 (NCHAINS / 4)     // float4 groups: 131072 threads
#define GROUP 8                    // steps per phase (8 x 16 B = 8 KB/wave bursts)
#define NGROUPS (T_STEPS / GROUP)  // 8 phases

typedef float vfloat4 __attribute__((ext_vector_type(4)));

// All macro indices are literal constants after expansion -> everything stays in
// registers (runtime-indexed ext_vector arrays would go to scratch).

#define LOAD_GROUP(BUF, G)                                                      \
  {                                                                             \
    _Pragma("unroll")                                                           \
    for (int j = 0; j < GROUP; ++j)                                             \
      BUF[j] = __builtin_nontemporal_load(&in[((G) * GROUP + j) * NCHAINS4 + i]); \
  }

#define STEP_GROUP(BUF, G)                                                      \
  {                                                                             \
    vfloat4 ov[GROUP];                                                          \
    _Pragma("unroll")                                                           \
    for (int j = 0; j < GROUP; ++j) {                                           \
      vfloat4 x = BUF[j];                                                       \
      float xe[4] = {x.x, x.y, x.z, x.w};                                       \
      _Pragma("unroll")                                                         \
      for (int e = 0; e < 4; ++e) {                                             \
        /* EXACT ref op order: s = (x + s) - a; s = max(s+1,0)-1; a = spikes */ \
        float sv = (xe[e] + s[e]) - a[e];                                       \
        sv = fmaxf(sv + 1.0f, 0.0f) - 1.0f;                                     \
        s[e] = sv;                                                              \
        a[e] = (sv > 0.0f) ? floorf(sv) : 0.0f;                                 \
      }                                                                         \
      vfloat4 av = {a[0], a[1], a[2], a[3]};                                    \
      ov[j] = av;                                                               \
    }                                                                           \
    _Pragma("unroll")                                                           \
    for (int j = 0; j < GROUP; ++j)                                             \
      __builtin_nontemporal_store(ov[j], &out[((G) * GROUP + j) * NCHAINS4 + i]); \
  }

__global__ __launch_bounds__(256) void spiking_kernel(
    const vfloat4* __restrict__ in, vfloat4* __restrict__ out) {
    const int i = blockIdx.x * blockDim.x + threadIdx.x;

    float s[4] = {0.f, 0.f, 0.f, 0.f};
    float a[4] = {0.f, 0.f, 0.f, 0.f};

    vfloat4 xa[GROUP], xb[GROUP];

    // Prologue: groups 0 and 1 in flight (16 loads, 16 KB/wave) before any compute.
    LOAD_GROUP(xa, 0);
    LOAD_GROUP(xb, 1);

    // Steady state: issue loads for g+1, then compute+store g.
    STEP_GROUP(xa, 0);
    LOAD_GROUP(xa, 2);
    STEP_GROUP(xb, 1);
    LOAD_GROUP(xb, 3);
    STEP_GROUP(xa, 2);
    LOAD_GROUP(xa, 4);
    STEP_GROUP(xb, 3);
    LOAD_GROUP(xb, 5);
    STEP_GROUP(xa, 4);
    LOAD_GROUP(xa, 6);
    STEP_GROUP(xb, 5);
    LOAD_GROUP(xb, 7);
    STEP_GROUP(xa, 6);
    STEP_GROUP(xb, 7);
}

extern "C" void kernel_launch(void* const* d_in, const int* in_sizes, int n_in,
                              void* d_out, int out_size, void* d_ws, size_t ws_size,
                              hipStream_t stream) {
    const vfloat4* in = (const vfloat4*)d_in[0];
    vfloat4* out = (vfloat4*)d_out;
    // 131072 threads / 256 = 512 blocks -> 2 blocks/CU, 8 waves/CU (structural cap:
    // each float4 chain is serial over T, so thread count is fixed at NCHAINS4)
    spiking_kernel<<<NCHAINS4 / 256, 256, 0, stream>>>(in, out);
}